// Round 1
// baseline (8140.993 us; speedup 1.0000x reference)
//
#include <hip/hip_runtime.h>
#include <math.h>

#define IN_F 256
#define OUT_F 64
#define RPB 256            // rows per bucket (row >> 8)
#define NBKT_MAX 512       // LDS sizing; runtime nbkt = ceil(N/RPB) = 391
#define BIN_C 8192         // edges per bin block
#define BIN_T 512          // bin block threads

// ---------------------------------------------------------------------------
__global__ __launch_bounds__(256) void zero_i_kernel(int* __restrict__ p, int n) {
  int t = blockIdx.x * blockDim.x + threadIdx.x;
  int stride = gridDim.x * blockDim.x;
  for (; t < n; t += stride) p[t] = 0;
}

// ---------------------------------------------------------------------------
// s0 = x @ W  [N,256]x[256,64] fp32. (unchanged from previous round)
__global__ __launch_bounds__(256) void gemm_kernel(const float* __restrict__ x,
    const float* __restrict__ W, float* __restrict__ s0, int N) {
  __shared__ float4 Wt4[64 * 64];  // Wt4[n*64 + (k4 ^ n)] = W[4k..4k+3][n], 64 KB
  float* Wtf = (float*)Wt4;
  for (int idx = threadIdx.x; idx < 64 * 256; idx += 256) {
    int k = idx >> 6, n = idx & 63;
    Wtf[(n * 64 + ((k >> 2) ^ n)) * 4 + (k & 3)] = W[idx];
  }
  __syncthreads();
  int lane = threadIdx.x & 63;
  int gw = (blockIdx.x * 256 + threadIdx.x) >> 6;
  int nw = (gridDim.x * 256) >> 6;
  const float4* wrow = &Wt4[lane * 64];
  for (int r = gw; r < N; r += nw) {
    int ru = __builtin_amdgcn_readfirstlane(r);
    const float4* xr = (const float4*)(x + (size_t)ru * IN_F);
    float acc = 0.f;
#pragma unroll 8
    for (int k4 = 0; k4 < 64; ++k4) {
      float4 xv = xr[k4];
      float4 wv = wrow[k4 ^ lane];
      acc = fmaf(xv.x, wv.x, acc);
      acc = fmaf(xv.y, wv.y, acc);
      acc = fmaf(xv.z, wv.z, acc);
      acc = fmaf(xv.w, wv.w, acc);
    }
    s0[(size_t)ru * OUT_F + lane] = acc;
  }
}

// ---------------------------------------------------------------------------
// Coarse bucket histogram (LDS-private, then one global atomic per bucket).
__global__ __launch_bounds__(256) void bhist_kernel(const int* __restrict__ r0,
    const int* __restrict__ r1, const int* __restrict__ r2,
    const int* __restrict__ r3, int* __restrict__ bcnt, int E, int nbkt) {
  int op = blockIdx.y;
  const int* rows = (op == 0) ? r0 : (op == 1) ? r1 : (op == 2) ? r2 : r3;
  int* c = bcnt + op * nbkt;
  __shared__ int h[NBKT_MAX];
  for (int i = threadIdx.x; i < nbkt; i += 256) h[i] = 0;
  __syncthreads();
  int t = blockIdx.x * 256 + threadIdx.x;
  int stride = gridDim.x * 256;
  for (; t < E; t += stride) atomicAdd(&h[rows[t] >> 8], 1);
  __syncthreads();
  for (int i = threadIdx.x; i < nbkt; i += 256)
    if (h[i]) atomicAdd(&c[i], h[i]);
}

// Exclusive scan of bucket counts -> bbase[0..nbkt] and cursor copy bcur.
__global__ __launch_bounds__(512) void bscan_kernel(const int* __restrict__ bcnt,
    int* __restrict__ bbase, int* __restrict__ bcur, int nbkt) {
  int op = blockIdx.x;
  const int* c = bcnt + op * nbkt;
  int* bb = bbase + op * (nbkt + 1);
  int* bc = bcur + op * nbkt;
  __shared__ int sb[512];
  int t = threadIdx.x;
  int v = (t < nbkt) ? c[t] : 0;
  sb[t] = v;
  __syncthreads();
  for (int s = 1; s < 512; s <<= 1) {
    int u = (t >= s) ? sb[t - s] : 0;
    __syncthreads();
    sb[t] += u;
    __syncthreads();
  }
  if (t < nbkt) {
    int ex = sb[t] - v;
    bb[t] = ex;
    bc[t] = ex;
  }
  if (t == 0) bb[nbkt] = sb[nbkt - 1];
}

// ---------------------------------------------------------------------------
// Bin edges into bucket-contiguous regions of S with LDS staging so global
// writes are ~21-record coalesced runs (vs 8B random scatter = 8x write amp).
// Record: (col | rowlo<<17, val) -- row order within a bucket is arbitrary.
__global__ __launch_bounds__(BIN_T) void bin_kernel(
    const int* __restrict__ r0, const int* __restrict__ r1,
    const int* __restrict__ r2, const int* __restrict__ r3,
    const float* __restrict__ v0, const float* __restrict__ v1,
    const float* __restrict__ v2, const float* __restrict__ v3,
    int* __restrict__ bcur, uint2* __restrict__ S, int E, int nbkt) {
  int op = blockIdx.y;
  const int* rows = (op == 0) ? r0 : (op == 1) ? r1 : (op == 2) ? r2 : r3;
  const float* val = (op == 0) ? v0 : (op == 1) ? v1 : (op == 2) ? v2 : v3;
  const int* cols = rows + E;
  uint2* So = S + (size_t)op * E;
  int* cur = bcur + op * nbkt;

  __shared__ uint2 st[BIN_C];          // 64 KB staged records
  __shared__ int h[NBKT_MAX];          // counts, then global bases
  __shared__ int lbase[NBKT_MAX + 1];  // local exclusive offsets
  __shared__ int lcur[NBKT_MAX];       // local cursors
  __shared__ int sc[BIN_T];            // scan temp

  int base = blockIdx.x * BIN_C;
  int cnt = min(BIN_C, E - base);

  for (int i = threadIdx.x; i < nbkt; i += BIN_T) h[i] = 0;
  __syncthreads();
  for (int i = threadIdx.x; i < cnt; i += BIN_T)
    atomicAdd(&h[rows[base + i] >> 8], 1);
  __syncthreads();
  // scan h -> lbase (exclusive), Hillis-Steele over 512
  int v = (threadIdx.x < nbkt) ? h[threadIdx.x] : 0;
  sc[threadIdx.x] = v;
  __syncthreads();
  for (int s = 1; s < BIN_T; s <<= 1) {
    int u = (threadIdx.x >= s) ? sc[threadIdx.x - s] : 0;
    __syncthreads();
    sc[threadIdx.x] += u;
    __syncthreads();
  }
  if (threadIdx.x < nbkt) {
    int ex = sc[threadIdx.x] - v;
    lbase[threadIdx.x] = ex;
    lcur[threadIdx.x] = ex;
  }
  if (threadIdx.x == 0) lbase[nbkt] = cnt;
  __syncthreads();
  // stage records grouped by bucket
  for (int i = threadIdx.x; i < cnt; i += BIN_T) {
    int r = rows[base + i];
    int bk = r >> 8;
    unsigned p = (unsigned)cols[base + i] | ((unsigned)(r & 255) << 17);
    int slot = atomicAdd(&lcur[bk], 1);
    st[slot] = make_uint2(p, __float_as_uint(val[base + i]));
  }
  __syncthreads();
  // bulk-reserve global space per bucket (one atomic per block-bucket)
  for (int bk = threadIdx.x; bk < nbkt; bk += BIN_T) {
    int c = lbase[bk + 1] - lbase[bk];
    h[bk] = c ? atomicAdd(&cur[bk], c) : 0;
  }
  __syncthreads();
  // write out: consecutive slots in a bucket -> consecutive global addresses
  for (int j = threadIdx.x; j < cnt; j += BIN_T) {
    int lo = 0, hi = nbkt;  // binary search: lbase[lo] <= j < lbase[lo+1]
    while (hi - lo > 1) {
      int mid = (lo + hi) >> 1;
      if (lbase[mid] <= j) lo = mid; else hi = mid;
    }
    So[h[lo] + (j - lbase[lo])] = st[j];
  }
}

// ---------------------------------------------------------------------------
// SpMM over bucket-grouped (unsorted-within-bucket) edges. One block per
// bucket holds the 256x64 fp32 output tile in LDS; edges consumed in any
// order via native ds_add_f32. acc[rowlo*64+lane]: 2-way bank alias = free.
__global__ __launch_bounds__(512) void spmm_lds(const uint2* __restrict__ S,
    const int* __restrict__ bbase, const float* __restrict__ xin,
    float* __restrict__ out, int N, int Estride, int nbkt, int remap) {
  int op = blockIdx.y;
  S += (size_t)op * Estride;
  bbase += op * (nbkt + 1);
  if (remap)  // batched call: op0 -> chan0 (hA), op1..3 -> chan3..5 (hs1..3)
    out += (size_t)((op == 0) ? 0 : (op + 2)) * (size_t)N * OUT_F;

  __shared__ float4 acc4[RPB * OUT_F / 4];  // 64 KB
  float* acc = (float*)acc4;
  int b = blockIdx.x;
  int s = bbase[b], e = bbase[b + 1];
  int rowbase = b * RPB;
  int nrows = min(RPB, N - rowbase);

  for (int i = threadIdx.x; i < RPB * OUT_F / 4; i += 512)
    acc4[i] = make_float4(0.f, 0.f, 0.f, 0.f);
  __syncthreads();

  int lane = threadIdx.x & 63;
  int w = threadIdx.x >> 6;  // 8 waves
  int j = s + w;
  for (; j + 24 < e; j += 32) {
    uint2 e0 = S[j], e1 = S[j + 8], e2 = S[j + 16], e3 = S[j + 24];
    float g0 = xin[(size_t)(e0.x & 0x1FFFFu) * OUT_F + lane];
    float g1 = xin[(size_t)(e1.x & 0x1FFFFu) * OUT_F + lane];
    float g2 = xin[(size_t)(e2.x & 0x1FFFFu) * OUT_F + lane];
    float g3 = xin[(size_t)(e3.x & 0x1FFFFu) * OUT_F + lane];
    unsafeAtomicAdd(&acc[((e0.x >> 17) << 6) + lane], __uint_as_float(e0.y) * g0);
    unsafeAtomicAdd(&acc[((e1.x >> 17) << 6) + lane], __uint_as_float(e1.y) * g1);
    unsafeAtomicAdd(&acc[((e2.x >> 17) << 6) + lane], __uint_as_float(e2.y) * g2);
    unsafeAtomicAdd(&acc[((e3.x >> 17) << 6) + lane], __uint_as_float(e3.y) * g3);
  }
  for (; j < e; j += 8) {
    uint2 ed = S[j];
    float g = xin[(size_t)(ed.x & 0x1FFFFu) * OUT_F + lane];
    unsafeAtomicAdd(&acc[((ed.x >> 17) << 6) + lane], __uint_as_float(ed.y) * g);
  }
  __syncthreads();
  float4* o4 = (float4*)(out + (size_t)rowbase * OUT_F);
  for (int i = threadIdx.x; i < nrows * (OUT_F / 4); i += 512) o4[i] = acc4[i];
}

// ---------------------------------------------------------------------------
// Fused epilogue: e (raw-reshape dots), softmax, attention store, h_prime.
// (unchanged from previous round)
__global__ __launch_bounds__(256) void fuse_kernel(const float* __restrict__ s0,
    const float* __restrict__ chan, const float* __restrict__ a,
    float* __restrict__ out_h, float* __restrict__ out_att, int N) {
  int lane = threadIdx.x & 63;
  int i = (blockIdx.x * blockDim.x + threadIdx.x) >> 6;
  if (i >= N) return;
  size_t NF = (size_t)N * OUT_F;
  float e[6];
  int half = N >> 1;
  if (i < half) {
    float lo = s0[(size_t)(2 * i) * OUT_F + lane];
    float hi = s0[(size_t)(2 * i + 1) * OUT_F + lane];
#pragma unroll
    for (int ch = 0; ch < 6; ++ch) {
      float p = fmaf(lo, a[ch * 128 + lane], hi * a[ch * 128 + 64 + lane]);
#pragma unroll
      for (int off = 32; off; off >>= 1) p += __shfl_xor(p, off);
      e[ch] = p;
    }
  } else {
    int r = 2 * i - N;
#pragma unroll
    for (int ch = 0; ch < 6; ++ch) {
      float lo = chan[(size_t)ch * NF + (size_t)r * OUT_F + lane];
      float hi = chan[(size_t)ch * NF + (size_t)(r + 1) * OUT_F + lane];
      if (ch >= 3) { lo = fabsf(lo); hi = fabsf(hi); }
      float p = fmaf(lo, a[ch * 128 + lane], hi * a[ch * 128 + 64 + lane]);
#pragma unroll
      for (int off = 32; off; off >>= 1) p += __shfl_xor(p, off);
      e[ch] = p;
    }
  }
  float m = e[0];
#pragma unroll
  for (int ch = 1; ch < 6; ++ch) m = fmaxf(m, e[ch]);
  float s = 0.f;
#pragma unroll
  for (int ch = 0; ch < 6; ++ch) { e[ch] = expf(e[ch] - m); s += e[ch]; }
  float inv = 1.f / s;
#pragma unroll
  for (int ch = 0; ch < 6; ++ch) e[ch] *= inv;

  if (lane < 6) {
    float v = e[0];
    if (lane == 1) v = e[1];
    if (lane == 2) v = e[2];
    if (lane == 3) v = e[3];
    if (lane == 4) v = e[4];
    if (lane == 5) v = e[5];
    out_att[(size_t)i * 6 + lane] = v;
  }

  float hp = 0.f;
#pragma unroll
  for (int p = 0; p < 6; ++p) {
    int idx = p * 64 + lane;
    int c = idx % 6;
    int j = idx / 6;
    float v = chan[(size_t)c * NF + (size_t)i * OUT_F + j];
    v = (c >= 3) ? fabsf(v) : v;
    hp = fmaf(e[p], v, hp);
  }
  out_h[(size_t)i * OUT_F + lane] = hp * (1.f / 6.f);
}

// ---------------------------------------------------------------------------
extern "C" void kernel_launch(void* const* d_in, const int* in_sizes, int n_in,
                              void* d_out, int out_size, void* d_ws, size_t ws_size,
                              hipStream_t stream) {
  const float* x      = (const float*)d_in[0];
  const float* W      = (const float*)d_in[1];
  const float* a      = (const float*)d_in[2];
  const int*   A_idx  = (const int*)d_in[3];
  const float* A_val  = (const float*)d_in[4];
  const int*   P1_idx = (const int*)d_in[5];
  const float* P1_val = (const float*)d_in[6];
  const int*   P2_idx = (const int*)d_in[7];
  const float* P2_val = (const float*)d_in[8];
  const int*   P3_idx = (const int*)d_in[9];
  const float* P3_val = (const float*)d_in[10];

  int N = in_sizes[0] / IN_F;  // 100000
  int E = in_sizes[4];         // 3200000
  int nbkt = (N + RPB - 1) / RPB;  // 391 (<= NBKT_MAX)

  size_t NF = (size_t)N * OUT_F;
  float* s0   = (float*)d_ws;
  float* chan = s0 + NF;               // 6 contiguous [N,64] channel buffers
  float* hA   = chan + 0 * NF;
  float* hA2  = chan + 1 * NF;
  float* hA3  = chan + 2 * NF;
  float* hs1  = chan + 3 * NF;

  float* out_h   = (float*)d_out;
  float* out_att = out_h + NF;

  int fblocks = (N * 64 + 255) / 256;
  int binblocks = (E + BIN_C - 1) / BIN_C;

  // Primary layout: S[4E] records (A, P1, P2, P3), then small int arrays.
  uint2* S    = (uint2*)(chan + 6 * NF);
  int* bcnt   = (int*)(S + (size_t)4 * E);
  int* bbase  = bcnt + 4 * nbkt;
  int* bcur   = bbase + 4 * (nbkt + 1);
  size_t need = (size_t)((char*)(bcur + 4 * nbkt) - (char*)d_ws);

  gemm_kernel<<<512, 256, 0, stream>>>(x, W, s0, N);

  if (ws_size >= need) {
    // ---- all 4 operators binned in one batched pipeline ----
    zero_i_kernel<<<4, 256, 0, stream>>>(bcnt, 4 * nbkt);
    bhist_kernel<<<dim3(512, 4), 256, 0, stream>>>(A_idx, P1_idx, P2_idx, P3_idx,
        bcnt, E, nbkt);
    bscan_kernel<<<4, 512, 0, stream>>>(bcnt, bbase, bcur, nbkt);
    bin_kernel<<<dim3(binblocks, 4), BIN_T, 0, stream>>>(A_idx, P1_idx, P2_idx,
        P3_idx, A_val, P1_val, P2_val, P3_val, bcur, S, E, nbkt);
    // hA + hs1..hs3 all read s0 -> one 4-op batch; then A chain.
    spmm_lds<<<dim3(nbkt, 4), 512, 0, stream>>>(S, bbase, s0, chan, N, E, nbkt, 1);
    spmm_lds<<<dim3(nbkt, 1), 512, 0, stream>>>(S, bbase, hA,  hA2, N, E, nbkt, 0);
    spmm_lds<<<dim3(nbkt, 1), 512, 0, stream>>>(S, bbase, hA2, hA3, N, E, nbkt, 0);
  } else {
    // ---- sequential fallback: one shared S[E] staging region ----
    int* bcnt1  = (int*)(S + (size_t)E);
    int* bbase1 = bcnt1 + nbkt;
    int* bcur1  = bbase1 + (nbkt + 1);
    const int*   RI[4] = {A_idx, P1_idx, P2_idx, P3_idx};
    const float* RV[4] = {A_val, P1_val, P2_val, P3_val};
    for (int o = 0; o < 4; ++o) {
      zero_i_kernel<<<2, 256, 0, stream>>>(bcnt1, nbkt);
      bhist_kernel<<<dim3(512, 1), 256, 0, stream>>>(RI[o], RI[o], RI[o], RI[o],
          bcnt1, E, nbkt);
      bscan_kernel<<<1, 512, 0, stream>>>(bcnt1, bbase1, bcur1, nbkt);
      bin_kernel<<<dim3(binblocks, 1), BIN_T, 0, stream>>>(RI[o], RI[o], RI[o],
          RI[o], RV[o], RV[o], RV[o], RV[o], bcur1, S, E, nbkt);
      float* outp = (o == 0) ? hA : hs1 + (size_t)(o - 1) * NF;
      spmm_lds<<<dim3(nbkt, 1), 512, 0, stream>>>(S, bbase1, s0, outp, N, E, nbkt, 0);
      if (o == 0) {
        spmm_lds<<<dim3(nbkt, 1), 512, 0, stream>>>(S, bbase1, hA,  hA2, N, E, nbkt, 0);
        spmm_lds<<<dim3(nbkt, 1), 512, 0, stream>>>(S, bbase1, hA2, hA3, N, E, nbkt, 0);
      }
    }
  }

  fuse_kernel<<<fblocks, 256, 0, stream>>>(s0, chan, a, out_h, out_att, N);
}

// Round 3
// 1563.852 us; speedup vs baseline: 5.2057x; 5.2057x over previous
//
#include <hip/hip_runtime.h>
#include <math.h>

#define IN_F 256
#define OUT_F 64
#define RPB 256            // rows per bucket (row >> 8)
#define NBKT_MAX 512       // LDS sizing; runtime nbkt = ceil(N/RPB) = 391
#define BIN_C 8192         // edges per bin block
#define BIN_T 512          // bin block threads

// ---------------------------------------------------------------------------
__global__ __launch_bounds__(256) void zero_i_kernel(int* __restrict__ p, int n) {
  int t = blockIdx.x * blockDim.x + threadIdx.x;
  int stride = gridDim.x * blockDim.x;
  for (; t < n; t += stride) p[t] = 0;
}

// ---------------------------------------------------------------------------
// s0 = x @ W  [N,256]x[256,64] fp32. (proven kernel, unchanged)
__global__ __launch_bounds__(256) void gemm_kernel(const float* __restrict__ x,
    const float* __restrict__ W, float* __restrict__ s0, int N) {
  __shared__ float4 Wt4[64 * 64];  // Wt4[n*64 + (k4 ^ n)] = W[4k..4k+3][n], 64 KB
  float* Wtf = (float*)Wt4;
  for (int idx = threadIdx.x; idx < 64 * 256; idx += 256) {
    int k = idx >> 6, n = idx & 63;
    Wtf[(n * 64 + ((k >> 2) ^ n)) * 4 + (k & 3)] = W[idx];
  }
  __syncthreads();
  int lane = threadIdx.x & 63;
  int gw = (blockIdx.x * 256 + threadIdx.x) >> 6;
  int nw = (gridDim.x * 256) >> 6;
  const float4* wrow = &Wt4[lane * 64];
  for (int r = gw; r < N; r += nw) {
    int ru = __builtin_amdgcn_readfirstlane(r);
    const float4* xr = (const float4*)(x + (size_t)ru * IN_F);
    float acc = 0.f;
#pragma unroll 8
    for (int k4 = 0; k4 < 64; ++k4) {
      float4 xv = xr[k4];
      float4 wv = wrow[k4 ^ lane];
      acc = fmaf(xv.x, wv.x, acc);
      acc = fmaf(xv.y, wv.y, acc);
      acc = fmaf(xv.z, wv.z, acc);
      acc = fmaf(xv.w, wv.w, acc);
    }
    s0[(size_t)ru * OUT_F + lane] = acc;
  }
}

// ---------------------------------------------------------------------------
// Coarse bucket histogram (LDS-private, then one global atomic per bucket).
// op = blockIdx.y + op_off selects source; blockIdx.y selects buffer slot.
__global__ __launch_bounds__(256) void bhist_kernel(const int* __restrict__ r0,
    const int* __restrict__ r1, const int* __restrict__ r2,
    const int* __restrict__ r3, int* __restrict__ bcnt, int E, int nbkt,
    int op_off) {
  int op = blockIdx.y + op_off;
  const int* rows = (op == 0) ? r0 : (op == 1) ? r1 : (op == 2) ? r2 : r3;
  int* c = bcnt + blockIdx.y * nbkt;
  __shared__ int h[NBKT_MAX];
  for (int i = threadIdx.x; i < nbkt; i += 256) h[i] = 0;
  __syncthreads();
  int t = blockIdx.x * 256 + threadIdx.x;
  int stride = gridDim.x * 256;
  for (; t < E; t += stride) atomicAdd(&h[rows[t] >> 8], 1);
  __syncthreads();
  for (int i = threadIdx.x; i < nbkt; i += 256)
    if (h[i]) atomicAdd(&c[i], h[i]);
}

// Exclusive scan of bucket counts -> bbase[0..nbkt] and cursor copy bcur.
__global__ __launch_bounds__(512) void bscan_kernel(const int* __restrict__ bcnt,
    int* __restrict__ bbase, int* __restrict__ bcur, int nbkt) {
  int op = blockIdx.x;
  const int* c = bcnt + op * nbkt;
  int* bb = bbase + op * (nbkt + 1);
  int* bc = bcur + op * nbkt;
  __shared__ int sb[512];
  int t = threadIdx.x;
  int v = (t < nbkt) ? c[t] : 0;
  sb[t] = v;
  __syncthreads();
  for (int s = 1; s < 512; s <<= 1) {
    int u = (t >= s) ? sb[t - s] : 0;
    __syncthreads();
    sb[t] += u;
    __syncthreads();
  }
  if (t < nbkt) {
    int ex = sb[t] - v;
    bb[t] = ex;
    bc[t] = ex;
  }
  if (t == 0) bb[nbkt] = sb[nbkt - 1];
}

// ---------------------------------------------------------------------------
// Bin edges into bucket-contiguous regions with LDS staging so global writes
// are ~21-record coalesced runs. Record: (col | rowlo<<17, val).
__global__ __launch_bounds__(BIN_T) void bin_kernel(
    const int* __restrict__ r0, const int* __restrict__ r1,
    const int* __restrict__ r2, const int* __restrict__ r3,
    const float* __restrict__ v0, const float* __restrict__ v1,
    const float* __restrict__ v2, const float* __restrict__ v3,
    int* __restrict__ bcur, uint2* __restrict__ S, int E, int nbkt,
    int op_off) {
  int op = blockIdx.y + op_off;
  const int* rows = (op == 0) ? r0 : (op == 1) ? r1 : (op == 2) ? r2 : r3;
  const float* val = (op == 0) ? v0 : (op == 1) ? v1 : (op == 2) ? v2 : v3;
  const int* cols = rows + E;
  uint2* So = S + (size_t)blockIdx.y * E;
  int* cur = bcur + blockIdx.y * nbkt;

  __shared__ uint2 st[BIN_C];          // 64 KB staged records
  __shared__ int h[NBKT_MAX];          // counts, then global bases
  __shared__ int lbase[NBKT_MAX + 1];  // local exclusive offsets
  __shared__ int lcur[NBKT_MAX];       // local cursors
  __shared__ int sc[BIN_T];            // scan temp

  int base = blockIdx.x * BIN_C;
  int cnt = min(BIN_C, E - base);

  for (int i = threadIdx.x; i < nbkt; i += BIN_T) h[i] = 0;
  __syncthreads();
  for (int i = threadIdx.x; i < cnt; i += BIN_T)
    atomicAdd(&h[rows[base + i] >> 8], 1);
  __syncthreads();
  int v = (threadIdx.x < nbkt) ? h[threadIdx.x] : 0;
  sc[threadIdx.x] = v;
  __syncthreads();
  for (int s = 1; s < BIN_T; s <<= 1) {
    int u = (threadIdx.x >= s) ? sc[threadIdx.x - s] : 0;
    __syncthreads();
    sc[threadIdx.x] += u;
    __syncthreads();
  }
  if (threadIdx.x < nbkt) {
    int ex = sc[threadIdx.x] - v;
    lbase[threadIdx.x] = ex;
    lcur[threadIdx.x] = ex;
  }
  if (threadIdx.x == 0) lbase[nbkt] = cnt;
  __syncthreads();
  for (int i = threadIdx.x; i < cnt; i += BIN_T) {
    int r = rows[base + i];
    int bk = r >> 8;
    unsigned p = (unsigned)cols[base + i] | ((unsigned)(r & 255) << 17);
    int slot = atomicAdd(&lcur[bk], 1);
    st[slot] = make_uint2(p, __float_as_uint(val[base + i]));
  }
  __syncthreads();
  for (int bk = threadIdx.x; bk < nbkt; bk += BIN_T) {
    int c = lbase[bk + 1] - lbase[bk];
    h[bk] = c ? atomicAdd(&cur[bk], c) : 0;
  }
  __syncthreads();
  for (int j = threadIdx.x; j < cnt; j += BIN_T) {
    int lo = 0, hi = nbkt;  // binary search: lbase[lo] <= j < lbase[lo+1]
    while (hi - lo > 1) {
      int mid = (lo + hi) >> 1;
      if (lbase[mid] <= j) lo = mid; else hi = mid;
    }
    So[h[lo] + (j - lbase[lo])] = st[j];
  }
}

// ---------------------------------------------------------------------------
// One block per bucket: exact CSR sort within the bucket + emit off[] row
// ends from a 256-entry LDS histogram/scan. Scatter writes land inside the
// bucket's own 64KB output window (L2-resident), so HBM write amp is small.
// Bucket bin range == CSR range (bucket-count scan == CSR bucket start).
__global__ __launch_bounds__(512) void bucket_sort_kernel(
    const uint2* __restrict__ src, const int* __restrict__ bbase,
    uint2* __restrict__ dst, int* __restrict__ off, int E, int N, int nbkt) {
  src   += (size_t)blockIdx.y * E;
  dst   += (size_t)blockIdx.y * E;
  off   += (size_t)blockIdx.y * N;
  bbase += blockIdx.y * (nbkt + 1);
  int b = blockIdx.x;
  int s = bbase[b], e = bbase[b + 1];
  int rowbase = b << 8;
  int nrows = min(RPB, N - rowbase);

  __shared__ int rcnt[RPB];
  __shared__ int rend[RPB];   // inclusive scan
  __shared__ int lcur[RPB];
  if (threadIdx.x < RPB) rcnt[threadIdx.x] = 0;
  __syncthreads();
  for (int i = s + threadIdx.x; i < e; i += 512)
    atomicAdd(&rcnt[src[i].x >> 17], 1);
  __syncthreads();
  if (threadIdx.x < RPB) rend[threadIdx.x] = rcnt[threadIdx.x];
  __syncthreads();
  for (int st = 1; st < RPB; st <<= 1) {
    int u = 0;
    if (threadIdx.x < RPB && threadIdx.x >= st) u = rend[threadIdx.x - st];
    __syncthreads();
    if (threadIdx.x < RPB) rend[threadIdx.x] += u;
    __syncthreads();
  }
  if (threadIdx.x < nrows) off[rowbase + threadIdx.x] = s + rend[threadIdx.x];
  if (threadIdx.x < RPB)
    lcur[threadIdx.x] = s + rend[threadIdx.x] - rcnt[threadIdx.x];
  __syncthreads();
  for (int i = s + threadIdx.x; i < e; i += 512) {
    uint2 rec = src[i];
    int pos = atomicAdd(&lcur[rec.x >> 17], 1);
    dst[pos] = make_uint2(rec.x & 0x1FFFFu, rec.y);
  }
}

// ---------------------------------------------------------------------------
// Gather SpMM: wave per row, lane = feature. (proven round-0 kernel)
// remap=1 (batched 4-op call): op0 -> chan0 (hA), op1..3 -> chan3..5 (hs1..3).
__global__ __launch_bounds__(256) void spmm_gather(const uint2* __restrict__ S,
    const int* __restrict__ offEnd, const float* __restrict__ xin,
    float* __restrict__ out, int N, int Estride, int remap) {
  int op = blockIdx.y;
  S      += (size_t)op * Estride;
  offEnd += (size_t)op * N;
  int ch = remap ? ((op == 0) ? 0 : (op + 2)) : op;
  out    += (size_t)ch * (size_t)N * OUT_F;
  int lane = threadIdx.x & 63;
  int r = (blockIdx.x * 256 + threadIdx.x) >> 6;
  if (r >= N) return;
  r = __builtin_amdgcn_readfirstlane(r);
  int s = (r == 0) ? 0 : offEnd[r - 1];
  int e = offEnd[r];
  float acc = 0.f;
  int j = s;
  for (; j + 4 <= e; j += 4) {
    uint2 e0 = S[j], e1 = S[j + 1], e2 = S[j + 2], e3 = S[j + 3];
    float g0 = xin[(size_t)e0.x * OUT_F + lane];
    float g1 = xin[(size_t)e1.x * OUT_F + lane];
    float g2 = xin[(size_t)e2.x * OUT_F + lane];
    float g3 = xin[(size_t)e3.x * OUT_F + lane];
    acc = fmaf(__uint_as_float(e0.y), g0, acc);
    acc = fmaf(__uint_as_float(e1.y), g1, acc);
    acc = fmaf(__uint_as_float(e2.y), g2, acc);
    acc = fmaf(__uint_as_float(e3.y), g3, acc);
  }
  for (; j < e; ++j) {
    uint2 ed = S[j];
    acc = fmaf(__uint_as_float(ed.y), xin[(size_t)ed.x * OUT_F + lane], acc);
  }
  out[(size_t)r * OUT_F + lane] = acc;
}

// ---------------------------------------------------------------------------
// Fused epilogue. (proven kernel, unchanged)
__global__ __launch_bounds__(256) void fuse_kernel(const float* __restrict__ s0,
    const float* __restrict__ chan, const float* __restrict__ a,
    float* __restrict__ out_h, float* __restrict__ out_att, int N) {
  int lane = threadIdx.x & 63;
  int i = (blockIdx.x * blockDim.x + threadIdx.x) >> 6;
  if (i >= N) return;
  size_t NF = (size_t)N * OUT_F;
  float e[6];
  int half = N >> 1;
  if (i < half) {
    float lo = s0[(size_t)(2 * i) * OUT_F + lane];
    float hi = s0[(size_t)(2 * i + 1) * OUT_F + lane];
#pragma unroll
    for (int ch = 0; ch < 6; ++ch) {
      float p = fmaf(lo, a[ch * 128 + lane], hi * a[ch * 128 + 64 + lane]);
#pragma unroll
      for (int off = 32; off; off >>= 1) p += __shfl_xor(p, off);
      e[ch] = p;
    }
  } else {
    int r = 2 * i - N;
#pragma unroll
    for (int ch = 0; ch < 6; ++ch) {
      float lo = chan[(size_t)ch * NF + (size_t)r * OUT_F + lane];
      float hi = chan[(size_t)ch * NF + (size_t)(r + 1) * OUT_F + lane];
      if (ch >= 3) { lo = fabsf(lo); hi = fabsf(hi); }
      float p = fmaf(lo, a[ch * 128 + lane], hi * a[ch * 128 + 64 + lane]);
#pragma unroll
      for (int off = 32; off; off >>= 1) p += __shfl_xor(p, off);
      e[ch] = p;
    }
  }
  float m = e[0];
#pragma unroll
  for (int ch = 1; ch < 6; ++ch) m = fmaxf(m, e[ch]);
  float s = 0.f;
#pragma unroll
  for (int ch = 0; ch < 6; ++ch) { e[ch] = expf(e[ch] - m); s += e[ch]; }
  float inv = 1.f / s;
#pragma unroll
  for (int ch = 0; ch < 6; ++ch) e[ch] *= inv;

  if (lane < 6) {
    float v = e[0];
    if (lane == 1) v = e[1];
    if (lane == 2) v = e[2];
    if (lane == 3) v = e[3];
    if (lane == 4) v = e[4];
    if (lane == 5) v = e[5];
    out_att[(size_t)i * 6 + lane] = v;
  }

  float hp = 0.f;
#pragma unroll
  for (int p = 0; p < 6; ++p) {
    int idx = p * 64 + lane;
    int c = idx % 6;
    int j = idx / 6;
    float v = chan[(size_t)c * NF + (size_t)i * OUT_F + j];
    v = (c >= 3) ? fabsf(v) : v;
    hp = fmaf(e[p], v, hp);
  }
  out_h[(size_t)i * OUT_F + lane] = hp * (1.f / 6.f);
}

// ---------------------------------------------------------------------------
extern "C" void kernel_launch(void* const* d_in, const int* in_sizes, int n_in,
                              void* d_out, int out_size, void* d_ws, size_t ws_size,
                              hipStream_t stream) {
  const float* x      = (const float*)d_in[0];
  const float* W      = (const float*)d_in[1];
  const float* a      = (const float*)d_in[2];
  const int*   A_idx  = (const int*)d_in[3];
  const float* A_val  = (const float*)d_in[4];
  const int*   P1_idx = (const int*)d_in[5];
  const float* P1_val = (const float*)d_in[6];
  const int*   P2_idx = (const int*)d_in[7];
  const float* P2_val = (const float*)d_in[8];
  const int*   P3_idx = (const int*)d_in[9];
  const float* P3_val = (const float*)d_in[10];

  int N = in_sizes[0] / IN_F;      // 100000
  int E = in_sizes[4];             // 3200000
  int nbkt = (N + RPB - 1) / RPB;  // 391 (<= NBKT_MAX)

  size_t NF = (size_t)N * OUT_F;
  float* s0   = (float*)d_ws;
  float* chan = s0 + NF;               // 6 contiguous [N,64] channel buffers
  float* hA   = chan + 0 * NF;
  float* hA2  = chan + 1 * NF;
  float* hA3  = chan + 2 * NF;
  float* hs1  = chan + 3 * NF;

  float* out_h   = (float*)d_out;
  float* out_att = out_h + NF;

  int fblocks = (N * 64 + 255) / 256;
  int gblocks = (N * 64 + 255) / 256;
  int binblocks = (E + BIN_C - 1) / BIN_C;

  gemm_kernel<<<512, 256, 0, stream>>>(x, W, s0, N);

  // Primary layout: bin_tmp aliases chan (4E*8B = 102.4MB <= 6NF*4B =
  // 153.6MB); it is dead before the first spmm_gather writes chan.
  uint2* bin_tmp = (uint2*)chan;
  uint2* S    = (uint2*)(chan + 6 * NF);  // sorted CSR records, 4E
  int* off    = (int*)(S + (size_t)4 * E);
  int* bcnt   = off + 4 * N;
  int* bbase  = bcnt + 4 * nbkt;
  int* bcur   = bbase + 4 * (nbkt + 1);
  size_t need = (size_t)((char*)(bcur + 4 * nbkt) - (char*)d_ws);

  if (ws_size >= need) {
    // ---- all 4 operators through one batched sort pipeline ----
    zero_i_kernel<<<4, 256, 0, stream>>>(bcnt, 4 * nbkt);
    bhist_kernel<<<dim3(512, 4), 256, 0, stream>>>(A_idx, P1_idx, P2_idx, P3_idx,
        bcnt, E, nbkt, 0);
    bscan_kernel<<<4, 512, 0, stream>>>(bcnt, bbase, bcur, nbkt);
    bin_kernel<<<dim3(binblocks, 4), BIN_T, 0, stream>>>(A_idx, P1_idx, P2_idx,
        P3_idx, A_val, P1_val, P2_val, P3_val, bcur, bin_tmp, E, nbkt, 0);
    bucket_sort_kernel<<<dim3(nbkt, 4), 512, 0, stream>>>(bin_tmp, bbase, S,
        off, E, N, nbkt);
    // First-level SpMMs (A,P1,P2,P3 all read s0) in one batch, then A chain.
    spmm_gather<<<dim3(gblocks, 4), 256, 0, stream>>>(S, off, s0, chan, N, E, 1);
    spmm_gather<<<dim3(gblocks, 1), 256, 0, stream>>>(S, off, hA,  hA2, N, 0, 0);
    spmm_gather<<<dim3(gblocks, 1), 256, 0, stream>>>(S, off, hA2, hA3, N, 0, 0);
  } else {
    // ---- sequential fallback: disjoint S1/tmp1 regions, one op at a time ----
    uint2* S1    = (uint2*)(chan + 6 * NF);  // E sorted records
    uint2* tmp1  = S1 + E;                   // E binned records (disjoint!)
    int* off1    = (int*)(tmp1 + (size_t)E); // 4N (per-op slices)
    int* bcnt1   = off1 + 4 * N;
    int* bbase1  = bcnt1 + nbkt;
    int* bcur1   = bbase1 + (nbkt + 1);
    for (int o = 0; o < 4; ++o) {
      zero_i_kernel<<<2, 256, 0, stream>>>(bcnt1, nbkt);
      bhist_kernel<<<dim3(512, 1), 256, 0, stream>>>(A_idx, P1_idx, P2_idx,
          P3_idx, bcnt1, E, nbkt, o);
      bscan_kernel<<<1, 512, 0, stream>>>(bcnt1, bbase1, bcur1, nbkt);
      bin_kernel<<<dim3(binblocks, 1), BIN_T, 0, stream>>>(A_idx, P1_idx, P2_idx,
          P3_idx, A_val, P1_val, P2_val, P3_val, bcur1, tmp1, E, nbkt, o);
      bucket_sort_kernel<<<dim3(nbkt, 1), 512, 0, stream>>>(tmp1, bbase1, S1,
          off1 + o * N, E, N, nbkt);
      if (o == 0) {
        spmm_gather<<<dim3(gblocks, 1), 256, 0, stream>>>(S1, off1, s0,  hA,  N, 0, 0);
        spmm_gather<<<dim3(gblocks, 1), 256, 0, stream>>>(S1, off1, hA,  hA2, N, 0, 0);
        spmm_gather<<<dim3(gblocks, 1), 256, 0, stream>>>(S1, off1, hA2, hA3, N, 0, 0);
      } else {
        spmm_gather<<<dim3(gblocks, 1), 256, 0, stream>>>(S1, off1 + o * N, s0,
            hs1 + (size_t)(o - 1) * NF, N, 0, 0);
      }
    }
  }

  fuse_kernel<<<fblocks, 256, 0, stream>>>(s0, chan, a, out_h, out_att, N);
}

// Round 4
// 1535.108 us; speedup vs baseline: 5.3032x; 1.0187x over previous
//
#include <hip/hip_runtime.h>
#include <math.h>

#define IN_F 256
#define OUT_F 64
#define RPB 256            // rows per bucket (row >> 8)
#define NBKT_MAX 512       // LDS sizing; runtime nbkt = ceil(N/RPB) = 391
#define BIN_C 8192         // edges per bin block
#define BIN_T 512          // bin block threads

typedef unsigned int uint2v __attribute__((ext_vector_type(2)));

// ---------------------------------------------------------------------------
__global__ __launch_bounds__(256) void zero_i_kernel(int* __restrict__ p, int n) {
  int t = blockIdx.x * blockDim.x + threadIdx.x;
  int stride = gridDim.x * blockDim.x;
  for (; t < n; t += stride) p[t] = 0;
}

// ---------------------------------------------------------------------------
// s0 = x @ W  [N,256]x[256,64] fp32. (proven kernel, unchanged)
__global__ __launch_bounds__(256) void gemm_kernel(const float* __restrict__ x,
    const float* __restrict__ W, float* __restrict__ s0, int N) {
  __shared__ float4 Wt4[64 * 64];  // Wt4[n*64 + (k4 ^ n)] = W[4k..4k+3][n], 64 KB
  float* Wtf = (float*)Wt4;
  for (int idx = threadIdx.x; idx < 64 * 256; idx += 256) {
    int k = idx >> 6, n = idx & 63;
    Wtf[(n * 64 + ((k >> 2) ^ n)) * 4 + (k & 3)] = W[idx];
  }
  __syncthreads();
  int lane = threadIdx.x & 63;
  int gw = (blockIdx.x * 256 + threadIdx.x) >> 6;
  int nw = (gridDim.x * 256) >> 6;
  const float4* wrow = &Wt4[lane * 64];
  for (int r = gw; r < N; r += nw) {
    int ru = __builtin_amdgcn_readfirstlane(r);
    const float4* xr = (const float4*)(x + (size_t)ru * IN_F);
    float acc = 0.f;
#pragma unroll 8
    for (int k4 = 0; k4 < 64; ++k4) {
      float4 xv = xr[k4];
      float4 wv = wrow[k4 ^ lane];
      acc = fmaf(xv.x, wv.x, acc);
      acc = fmaf(xv.y, wv.y, acc);
      acc = fmaf(xv.z, wv.z, acc);
      acc = fmaf(xv.w, wv.w, acc);
    }
    s0[(size_t)ru * OUT_F + lane] = acc;
  }
}

// ---------------------------------------------------------------------------
// Bin edges into PADDED per-bucket regions (bucket bk at [bk*cap, bk*cap+cnt))
// using global per-bucket cursors -- no pre-pass histogram needed. LDS staging
// keeps global writes as ~21-record coalesced runs.
// Record: (col | rowlo<<17, val).  cap is >25 sigma above the binomial max for
// uniform rows; a clamp guard prevents OOB if that assumption ever breaks.
__global__ __launch_bounds__(BIN_T) void bin_kernel(
    const int* __restrict__ r0, const int* __restrict__ r1,
    const int* __restrict__ r2, const int* __restrict__ r3,
    const float* __restrict__ v0, const float* __restrict__ v1,
    const float* __restrict__ v2, const float* __restrict__ v3,
    int* __restrict__ bcur, uint2* __restrict__ PB, int E, int nbkt, int cap,
    int op_off) {
  int op = blockIdx.y + op_off;
  const int* rows = (op == 0) ? r0 : (op == 1) ? r1 : (op == 2) ? r2 : r3;
  const float* val = (op == 0) ? v0 : (op == 1) ? v1 : (op == 2) ? v2 : v3;
  const int* cols = rows + E;
  uint2* So = PB + (size_t)blockIdx.y * nbkt * cap;
  int* cur = bcur + blockIdx.y * nbkt;

  __shared__ uint2 st[BIN_C];          // 64 KB staged records
  __shared__ int h[NBKT_MAX];          // counts, then padded-region bases
  __shared__ int lbase[NBKT_MAX + 1];  // local exclusive offsets
  __shared__ int lcur[NBKT_MAX];       // local cursors
  __shared__ int sc[BIN_T];            // scan temp

  int base = blockIdx.x * BIN_C;
  int cnt = min(BIN_C, E - base);

  for (int i = threadIdx.x; i < nbkt; i += BIN_T) h[i] = 0;
  __syncthreads();
  for (int i = threadIdx.x; i < cnt; i += BIN_T)
    atomicAdd(&h[rows[base + i] >> 8], 1);
  __syncthreads();
  int v = (threadIdx.x < nbkt) ? h[threadIdx.x] : 0;
  sc[threadIdx.x] = v;
  __syncthreads();
  for (int s = 1; s < BIN_T; s <<= 1) {
    int u = (threadIdx.x >= s) ? sc[threadIdx.x - s] : 0;
    __syncthreads();
    sc[threadIdx.x] += u;
    __syncthreads();
  }
  if (threadIdx.x < nbkt) {
    int ex = sc[threadIdx.x] - v;
    lbase[threadIdx.x] = ex;
    lcur[threadIdx.x] = ex;
  }
  if (threadIdx.x == 0) lbase[nbkt] = cnt;
  __syncthreads();
  for (int i = threadIdx.x; i < cnt; i += BIN_T) {
    int r = rows[base + i];
    int bk = r >> 8;
    unsigned p = (unsigned)cols[base + i] | ((unsigned)(r & 255) << 17);
    int slot = atomicAdd(&lcur[bk], 1);
    st[slot] = make_uint2(p, __float_as_uint(val[base + i]));
  }
  __syncthreads();
  // bulk-reserve padded-bucket space (one global atomic per block-bucket)
  for (int bk = threadIdx.x; bk < nbkt; bk += BIN_T) {
    int c = lbase[bk + 1] - lbase[bk];
    int pos = 0;
    if (c) {
      pos = atomicAdd(&cur[bk], c);
      if (pos + c > cap) pos = (cap > c) ? (cap - c) : 0;  // OOB guard (never hit)
    }
    h[bk] = bk * cap + pos;
  }
  __syncthreads();
  for (int j = threadIdx.x; j < cnt; j += BIN_T) {
    int lo = 0, hi = nbkt;  // binary search: lbase[lo] <= j < lbase[lo+1]
    while (hi - lo > 1) {
      int mid = (lo + hi) >> 1;
      if (lbase[mid] <= j) lo = mid; else hi = mid;
    }
    So[(size_t)h[lo] + (j - lbase[lo])] = st[j];
  }
}

// Exclusive scan of final bucket counts (in bcur) -> CSR bucket bases bbase.
__global__ __launch_bounds__(512) void bscan_kernel(const int* __restrict__ bcnt,
    int* __restrict__ bbase, int nbkt) {
  int op = blockIdx.x;
  const int* c = bcnt + op * nbkt;
  int* bb = bbase + op * (nbkt + 1);
  __shared__ int sb[512];
  int t = threadIdx.x;
  int v = (t < nbkt) ? c[t] : 0;
  sb[t] = v;
  __syncthreads();
  for (int s = 1; s < 512; s <<= 1) {
    int u = (t >= s) ? sb[t - s] : 0;
    __syncthreads();
    sb[t] += u;
    __syncthreads();
  }
  if (t < nbkt) bb[t] = sb[t] - v;  // exclusive
  if (t == 0) bb[nbkt] = sb[nbkt - 1];
}

// ---------------------------------------------------------------------------
// One block per bucket: exact CSR sort within the bucket + emit off[] row
// ends from a 256-entry LDS histogram/scan. Scatter writes land inside the
// bucket's own 64KB output window (L2-resident), so HBM write amp is small.
__global__ __launch_bounds__(512) void bucket_sort_kernel(
    const uint2* __restrict__ PB, const int* __restrict__ bcnt,
    const int* __restrict__ bbase, uint2* __restrict__ dst,
    int* __restrict__ off, int E, int N, int nbkt, int cap) {
  PB    += (size_t)blockIdx.y * nbkt * cap;
  bcnt  += blockIdx.y * nbkt;
  bbase += blockIdx.y * (nbkt + 1);
  dst   += (size_t)blockIdx.y * E;
  off   += (size_t)blockIdx.y * N;
  int b = blockIdx.x;
  const uint2* src = PB + (size_t)b * cap;
  int cnt = min(bcnt[b], cap);
  int s = bbase[b];
  int rowbase = b << 8;
  int nrows = min(RPB, N - rowbase);

  __shared__ int rcnt[RPB];
  __shared__ int rend[RPB];   // inclusive scan
  __shared__ int lcur[RPB];
  if (threadIdx.x < RPB) rcnt[threadIdx.x] = 0;
  __syncthreads();
  for (int i = threadIdx.x; i < cnt; i += 512)
    atomicAdd(&rcnt[src[i].x >> 17], 1);
  __syncthreads();
  if (threadIdx.x < RPB) rend[threadIdx.x] = rcnt[threadIdx.x];
  __syncthreads();
  for (int st = 1; st < RPB; st <<= 1) {
    int u = 0;
    if (threadIdx.x < RPB && threadIdx.x >= st) u = rend[threadIdx.x - st];
    __syncthreads();
    if (threadIdx.x < RPB) rend[threadIdx.x] += u;
    __syncthreads();
  }
  if (threadIdx.x < nrows) off[rowbase + threadIdx.x] = s + rend[threadIdx.x];
  if (threadIdx.x < RPB)
    lcur[threadIdx.x] = s + rend[threadIdx.x] - rcnt[threadIdx.x];
  __syncthreads();
  for (int i = threadIdx.x; i < cnt; i += 512) {
    uint2 rec = src[i];
    int pos = atomicAdd(&lcur[rec.x >> 17], 1);
    dst[pos] = make_uint2(rec.x & 0x1FFFFu, rec.y);
  }
}

// ---------------------------------------------------------------------------
// Gather SpMM: wave per row, lane = feature. Edge records fetched COALESCED
// (lane l loads record s+l, one 256-512B request per <=64 edges) and
// broadcast via shfl (VALU is idle); 8 gathers kept in flight per group.
// nt loads/stores keep the streaming records/outputs from evicting xin's
// rows out of L2. remap=1: op0 -> chan0 (hA), op1..3 -> chan3..5 (hs1..3).
__global__ __launch_bounds__(256) void spmm_gather(const uint2* __restrict__ S,
    const int* __restrict__ offEnd, const float* __restrict__ xin,
    float* __restrict__ out, int N, int Estride, int remap) {
  int op = blockIdx.y;
  S      += (size_t)op * Estride;
  offEnd += (size_t)op * N;
  int ch = remap ? ((op == 0) ? 0 : (op + 2)) : op;
  out    += (size_t)ch * (size_t)N * OUT_F;
  int lane = threadIdx.x & 63;
  int r = (blockIdx.x * 256 + threadIdx.x) >> 6;
  if (r >= N) return;
  r = __builtin_amdgcn_readfirstlane(r);
  int s = (r == 0) ? 0 : offEnd[r - 1];
  int e = offEnd[r];
  float acc = 0.f;
  for (int base = s; base < e; base += 64) {
    int m = e - base;
    if (m > 64) m = 64;
    uint2v rec = (uint2v)0u;
    if (lane < m)
      rec = __builtin_nontemporal_load((const uint2v*)S + (base + lane));
    int k = 0;
    for (; k + 8 <= m; k += 8) {
#pragma unroll
      for (int u = 0; u < 8; ++u) {
        int c = __shfl((int)rec.x, k + u);
        float w = __uint_as_float((unsigned)__shfl((int)rec.y, k + u));
        acc = fmaf(w, xin[(size_t)(unsigned)c * OUT_F + lane], acc);
      }
    }
    for (; k < m; ++k) {
      int c = __shfl((int)rec.x, k);
      float w = __uint_as_float((unsigned)__shfl((int)rec.y, k));
      acc = fmaf(w, xin[(size_t)(unsigned)c * OUT_F + lane], acc);
    }
  }
  __builtin_nontemporal_store(acc, &out[(size_t)r * OUT_F + lane]);
}

// ---------------------------------------------------------------------------
// Fused epilogue. (proven kernel, unchanged)
__global__ __launch_bounds__(256) void fuse_kernel(const float* __restrict__ s0,
    const float* __restrict__ chan, const float* __restrict__ a,
    float* __restrict__ out_h, float* __restrict__ out_att, int N) {
  int lane = threadIdx.x & 63;
  int i = (blockIdx.x * blockDim.x + threadIdx.x) >> 6;
  if (i >= N) return;
  size_t NF = (size_t)N * OUT_F;
  float e[6];
  int half = N >> 1;
  if (i < half) {
    float lo = s0[(size_t)(2 * i) * OUT_F + lane];
    float hi = s0[(size_t)(2 * i + 1) * OUT_F + lane];
#pragma unroll
    for (int ch = 0; ch < 6; ++ch) {
      float p = fmaf(lo, a[ch * 128 + lane], hi * a[ch * 128 + 64 + lane]);
#pragma unroll
      for (int off = 32; off; off >>= 1) p += __shfl_xor(p, off);
      e[ch] = p;
    }
  } else {
    int r = 2 * i - N;
#pragma unroll
    for (int ch = 0; ch < 6; ++ch) {
      float lo = chan[(size_t)ch * NF + (size_t)r * OUT_F + lane];
      float hi = chan[(size_t)ch * NF + (size_t)(r + 1) * OUT_F + lane];
      if (ch >= 3) { lo = fabsf(lo); hi = fabsf(hi); }
      float p = fmaf(lo, a[ch * 128 + lane], hi * a[ch * 128 + 64 + lane]);
#pragma unroll
      for (int off = 32; off; off >>= 1) p += __shfl_xor(p, off);
      e[ch] = p;
    }
  }
  float m = e[0];
#pragma unroll
  for (int ch = 1; ch < 6; ++ch) m = fmaxf(m, e[ch]);
  float s = 0.f;
#pragma unroll
  for (int ch = 0; ch < 6; ++ch) { e[ch] = expf(e[ch] - m); s += e[ch]; }
  float inv = 1.f / s;
#pragma unroll
  for (int ch = 0; ch < 6; ++ch) e[ch] *= inv;

  if (lane < 6) {
    float v = e[0];
    if (lane == 1) v = e[1];
    if (lane == 2) v = e[2];
    if (lane == 3) v = e[3];
    if (lane == 4) v = e[4];
    if (lane == 5) v = e[5];
    out_att[(size_t)i * 6 + lane] = v;
  }

  float hp = 0.f;
#pragma unroll
  for (int p = 0; p < 6; ++p) {
    int idx = p * 64 + lane;
    int c = idx % 6;
    int j = idx / 6;
    float v = chan[(size_t)c * NF + (size_t)i * OUT_F + j];
    v = (c >= 3) ? fabsf(v) : v;
    hp = fmaf(e[p], v, hp);
  }
  out_h[(size_t)i * OUT_F + lane] = hp * (1.f / 6.f);
}

// ---------------------------------------------------------------------------
extern "C" void kernel_launch(void* const* d_in, const int* in_sizes, int n_in,
                              void* d_out, int out_size, void* d_ws, size_t ws_size,
                              hipStream_t stream) {
  const float* x      = (const float*)d_in[0];
  const float* W      = (const float*)d_in[1];
  const float* a      = (const float*)d_in[2];
  const int*   A_idx  = (const int*)d_in[3];
  const float* A_val  = (const float*)d_in[4];
  const int*   P1_idx = (const int*)d_in[5];
  const float* P1_val = (const float*)d_in[6];
  const int*   P2_idx = (const int*)d_in[7];
  const float* P2_val = (const float*)d_in[8];
  const int*   P3_idx = (const int*)d_in[9];
  const float* P3_val = (const float*)d_in[10];

  int N = in_sizes[0] / IN_F;      // 100000
  int E = in_sizes[4];             // 3200000
  int nbkt = (N + RPB - 1) / RPB;  // 391 (<= NBKT_MAX)

  size_t NF = (size_t)N * OUT_F;
  float* s0   = (float*)d_ws;
  float* chan = s0 + NF;               // 6 contiguous [N,64] channel buffers
  float* hA   = chan + 0 * NF;
  float* hA2  = chan + 1 * NF;
  float* hA3  = chan + 2 * NF;
  float* hs1  = chan + 3 * NF;

  float* out_h   = (float*)d_out;
  float* out_att = out_h + NF;

  int fblocks = (N * 64 + 255) / 256;
  int gblocks = (N * 64 + 255) / 256;
  int binblocks = (E + BIN_C - 1) / BIN_C;

  // Padded-bucket capacity: mean + 25% + 256 (>25 sigma for uniform rows).
  int cap = E / nbkt + E / (4 * nbkt) + 256;
  // PB aliases chan; make sure 4 padded ops fit inside chan's 6NF floats.
  size_t pbcap_max = (6 * NF * 4) / ((size_t)4 * nbkt * 8);
  if ((size_t)cap > pbcap_max) cap = (int)pbcap_max;

  gemm_kernel<<<512, 256, 0, stream>>>(x, W, s0, N);

  // Primary layout: PB aliases chan (4*391*10486*8B = 131MB <= 153.6MB);
  // PB is dead before the first spmm_gather writes chan.
  uint2* PB   = (uint2*)chan;
  uint2* S    = (uint2*)(chan + 6 * NF);  // sorted CSR records, 4E
  int* off    = (int*)(S + (size_t)4 * E);
  int* bcur   = off + 4 * N;
  int* bbase  = bcur + 4 * nbkt;
  size_t need = (size_t)((char*)(bbase + 4 * (nbkt + 1)) - (char*)d_ws);

  if (ws_size >= need) {
    // ---- all 4 operators through one batched padded-bin pipeline ----
    zero_i_kernel<<<4, 256, 0, stream>>>(bcur, 4 * nbkt);
    bin_kernel<<<dim3(binblocks, 4), BIN_T, 0, stream>>>(A_idx, P1_idx, P2_idx,
        P3_idx, A_val, P1_val, P2_val, P3_val, bcur, PB, E, nbkt, cap, 0);
    bscan_kernel<<<4, 512, 0, stream>>>(bcur, bbase, nbkt);
    bucket_sort_kernel<<<dim3(nbkt, 4), 512, 0, stream>>>(PB, bcur, bbase, S,
        off, E, N, nbkt, cap);
    // First-level SpMMs (A,P1,P2,P3 all read s0) in one batch, then A chain.
    spmm_gather<<<dim3(gblocks, 4), 256, 0, stream>>>(S, off, s0, chan, N, E, 1);
    spmm_gather<<<dim3(gblocks, 1), 256, 0, stream>>>(S, off, hA,  hA2, N, 0, 0);
    spmm_gather<<<dim3(gblocks, 1), 256, 0, stream>>>(S, off, hA2, hA3, N, 0, 0);
  } else {
    // ---- sequential fallback: disjoint S1/PB1 regions, one op at a time ----
    uint2* S1    = (uint2*)(chan + 6 * NF);        // E sorted records
    uint2* PB1   = S1 + E;                         // nbkt*cap padded records
    int* off1    = (int*)(PB1 + (size_t)nbkt * cap);  // 4N (per-op slices)
    int* bcur1   = off1 + 4 * N;
    int* bbase1  = bcur1 + nbkt;
    for (int o = 0; o < 4; ++o) {
      zero_i_kernel<<<1, 256, 0, stream>>>(bcur1, nbkt);
      bin_kernel<<<dim3(binblocks, 1), BIN_T, 0, stream>>>(A_idx, P1_idx, P2_idx,
          P3_idx, A_val, P1_val, P2_val, P3_val, bcur1, PB1, E, nbkt, cap, o);
      bscan_kernel<<<1, 512, 0, stream>>>(bcur1, bbase1, nbkt);
      bucket_sort_kernel<<<dim3(nbkt, 1), 512, 0, stream>>>(PB1, bcur1, bbase1,
          S1, off1 + o * N, E, N, nbkt, cap);
      if (o == 0) {
        spmm_gather<<<dim3(gblocks, 1), 256, 0, stream>>>(S1, off1, s0,  hA,  N, 0, 0);
        spmm_gather<<<dim3(gblocks, 1), 256, 0, stream>>>(S1, off1, hA,  hA2, N, 0, 0);
        spmm_gather<<<dim3(gblocks, 1), 256, 0, stream>>>(S1, off1, hA2, hA3, N, 0, 0);
      } else {
        spmm_gather<<<dim3(gblocks, 1), 256, 0, stream>>>(S1, off1 + o * N, s0,
            hs1 + (size_t)(o - 1) * NF, N, 0, 0);
      }
    }
  }

  fuse_kernel<<<fblocks, 256, 0, stream>>>(s0, chan, a, out_h, out_att, N);
}

// Round 5
// 1265.993 us; speedup vs baseline: 6.4305x; 1.2126x over previous
//
#include <hip/hip_runtime.h>
#include <math.h>

#define IN_F 256
#define OUT_F 64
#define RPB 256            // rows per bucket (row >> 8)
#define NBKT_MAX 512       // LDS sizing; runtime nbkt = ceil(N/RPB) = 391
#define BIN_C 8192         // edges per bin block
#define BIN_T 512          // bin block threads

typedef unsigned int uint2v __attribute__((ext_vector_type(2)));

// ---------------------------------------------------------------------------
__global__ __launch_bounds__(256) void zero_i_kernel(int* __restrict__ p, int n) {
  int t = blockIdx.x * blockDim.x + threadIdx.x;
  int stride = gridDim.x * blockDim.x;
  for (; t < n; t += stride) p[t] = 0;
}

// ---------------------------------------------------------------------------
// s0 = x @ W  [N,256]x[256,64] fp32.
// Round-5 rewrite: old version fed each row as 64 wave-uniform sequential
// float4 loads (serial broadcast-load chain, latency-bound at 22% occupancy
// -> 393us). Now each wave handles 4 rows/iter: rows loaded COALESCED
// (lane l = float4 l of the row, 1KB/wave-load), parked in wave-private LDS
// (no barrier), consumed as wave-uniform ds_read broadcasts (bank-free).
// One W-fragment read is reused across the 4 rows (4x less full-rate LDS).
__global__ __launch_bounds__(256) void gemm_kernel(const float* __restrict__ x,
    const float* __restrict__ W, float* __restrict__ s0, int N) {
  __shared__ float4 Wt4[64 * 64];   // Wt4[n*64 + (k4 ^ n)] = W[4k..4k+3][n], 64 KB
  __shared__ float4 xb[4][4][64];   // [wave][row][k4], 16 KB, wave-private
  float* Wtf = (float*)Wt4;
  for (int idx = threadIdx.x; idx < 64 * 256; idx += 256) {
    int k = idx >> 6, n = idx & 63;          // W[k][n], coalesced global read
    Wtf[(n * 64 + ((k >> 2) ^ n)) * 4 + (k & 3)] = W[idx];
  }
  __syncthreads();
  int lane = threadIdx.x & 63;
  int wv = threadIdx.x >> 6;
  int gw = (blockIdx.x * 256 + threadIdx.x) >> 6;  // global wave id
  int nw = (gridDim.x * 256) >> 6;                 // total waves
  const float4* wrow = &Wt4[lane * 64];
  float4 (*myx)[64] = xb[wv];

  for (int g = gw; g * 4 < N; g += nw) {
    int r0 = g * 4;
    int nr = N - r0; if (nr > 4) nr = 4;
    float4 rw0, rw1, rw2, rw3;               // coalesced row loads
    rw0 = ((const float4*)(x + (size_t)r0 * IN_F))[lane];
    if (nr > 1) rw1 = ((const float4*)(x + (size_t)(r0 + 1) * IN_F))[lane];
    if (nr > 2) rw2 = ((const float4*)(x + (size_t)(r0 + 2) * IN_F))[lane];
    if (nr > 3) rw3 = ((const float4*)(x + (size_t)(r0 + 3) * IN_F))[lane];
    myx[0][lane] = rw0;
    if (nr > 1) myx[1][lane] = rw1;
    if (nr > 2) myx[2][lane] = rw2;
    if (nr > 3) myx[3][lane] = rw3;
    // wave-private LDS: compiler's lgkmcnt ordering suffices, no barrier.
    float a0 = 0.f, a1 = 0.f, a2 = 0.f, a3 = 0.f;
#pragma unroll 8
    for (int k4 = 0; k4 < 64; ++k4) {
      float4 w4 = wrow[k4 ^ lane];           // ds_read_b128, swizzled banks
      float4 xv = myx[0][k4];                // wave-uniform broadcast reads
      a0 = fmaf(xv.x, w4.x, a0); a0 = fmaf(xv.y, w4.y, a0);
      a0 = fmaf(xv.z, w4.z, a0); a0 = fmaf(xv.w, w4.w, a0);
      xv = myx[1][k4];
      a1 = fmaf(xv.x, w4.x, a1); a1 = fmaf(xv.y, w4.y, a1);
      a1 = fmaf(xv.z, w4.z, a1); a1 = fmaf(xv.w, w4.w, a1);
      xv = myx[2][k4];
      a2 = fmaf(xv.x, w4.x, a2); a2 = fmaf(xv.y, w4.y, a2);
      a2 = fmaf(xv.z, w4.z, a2); a2 = fmaf(xv.w, w4.w, a2);
      xv = myx[3][k4];
      a3 = fmaf(xv.x, w4.x, a3); a3 = fmaf(xv.y, w4.y, a3);
      a3 = fmaf(xv.z, w4.z, a3); a3 = fmaf(xv.w, w4.w, a3);
    }
    s0[(size_t)r0 * OUT_F + lane] = a0;
    if (nr > 1) s0[(size_t)(r0 + 1) * OUT_F + lane] = a1;
    if (nr > 2) s0[(size_t)(r0 + 2) * OUT_F + lane] = a2;
    if (nr > 3) s0[(size_t)(r0 + 3) * OUT_F + lane] = a3;
  }
}

// ---------------------------------------------------------------------------
// Bin edges into PADDED per-bucket regions (bucket bk at [bk*cap, bk*cap+cnt))
// using global per-bucket cursors -- no pre-pass histogram needed. LDS staging
// keeps global writes as ~21-record coalesced runs.
// Record: (col | rowlo<<17, val).  cap is >25 sigma above the binomial max for
// uniform rows; a clamp guard prevents OOB if that assumption ever breaks.
__global__ __launch_bounds__(BIN_T) void bin_kernel(
    const int* __restrict__ r0, const int* __restrict__ r1,
    const int* __restrict__ r2, const int* __restrict__ r3,
    const float* __restrict__ v0, const float* __restrict__ v1,
    const float* __restrict__ v2, const float* __restrict__ v3,
    int* __restrict__ bcur, uint2* __restrict__ PB, int E, int nbkt, int cap,
    int op_off) {
  int op = blockIdx.y + op_off;
  const int* rows = (op == 0) ? r0 : (op == 1) ? r1 : (op == 2) ? r2 : r3;
  const float* val = (op == 0) ? v0 : (op == 1) ? v1 : (op == 2) ? v2 : v3;
  const int* cols = rows + E;
  uint2* So = PB + (size_t)blockIdx.y * nbkt * cap;
  int* cur = bcur + blockIdx.y * nbkt;

  __shared__ uint2 st[BIN_C];          // 64 KB staged records
  __shared__ int h[NBKT_MAX];          // counts, then padded-region bases
  __shared__ int lbase[NBKT_MAX + 1];  // local exclusive offsets
  __shared__ int lcur[NBKT_MAX];       // local cursors
  __shared__ int sc[BIN_T];            // scan temp

  int base = blockIdx.x * BIN_C;
  int cnt = min(BIN_C, E - base);

  for (int i = threadIdx.x; i < nbkt; i += BIN_T) h[i] = 0;
  __syncthreads();
  for (int i = threadIdx.x; i < cnt; i += BIN_T)
    atomicAdd(&h[rows[base + i] >> 8], 1);
  __syncthreads();
  int v = (threadIdx.x < nbkt) ? h[threadIdx.x] : 0;
  sc[threadIdx.x] = v;
  __syncthreads();
  for (int s = 1; s < BIN_T; s <<= 1) {
    int u = (threadIdx.x >= s) ? sc[threadIdx.x - s] : 0;
    __syncthreads();
    sc[threadIdx.x] += u;
    __syncthreads();
  }
  if (threadIdx.x < nbkt) {
    int ex = sc[threadIdx.x] - v;
    lbase[threadIdx.x] = ex;
    lcur[threadIdx.x] = ex;
  }
  if (threadIdx.x == 0) lbase[nbkt] = cnt;
  __syncthreads();
  for (int i = threadIdx.x; i < cnt; i += BIN_T) {
    int r = rows[base + i];
    int bk = r >> 8;
    unsigned p = (unsigned)cols[base + i] | ((unsigned)(r & 255) << 17);
    int slot = atomicAdd(&lcur[bk], 1);
    st[slot] = make_uint2(p, __float_as_uint(val[base + i]));
  }
  __syncthreads();
  // bulk-reserve padded-bucket space (one global atomic per block-bucket)
  for (int bk = threadIdx.x; bk < nbkt; bk += BIN_T) {
    int c = lbase[bk + 1] - lbase[bk];
    int pos = 0;
    if (c) {
      pos = atomicAdd(&cur[bk], c);
      if (pos + c > cap) pos = (cap > c) ? (cap - c) : 0;  // OOB guard (never hit)
    }
    h[bk] = bk * cap + pos;
  }
  __syncthreads();
  for (int j = threadIdx.x; j < cnt; j += BIN_T) {
    int lo = 0, hi = nbkt;  // binary search: lbase[lo] <= j < lbase[lo+1]
    while (hi - lo > 1) {
      int mid = (lo + hi) >> 1;
      if (lbase[mid] <= j) lo = mid; else hi = mid;
    }
    So[(size_t)h[lo] + (j - lbase[lo])] = st[j];
  }
}

// Exclusive scan of final bucket counts (in bcur) -> CSR bucket bases bbase.
__global__ __launch_bounds__(512) void bscan_kernel(const int* __restrict__ bcnt,
    int* __restrict__ bbase, int nbkt) {
  int op = blockIdx.x;
  const int* c = bcnt + op * nbkt;
  int* bb = bbase + op * (nbkt + 1);
  __shared__ int sb[512];
  int t = threadIdx.x;
  int v = (t < nbkt) ? c[t] : 0;
  sb[t] = v;
  __syncthreads();
  for (int s = 1; s < 512; s <<= 1) {
    int u = (t >= s) ? sb[t - s] : 0;
    __syncthreads();
    sb[t] += u;
    __syncthreads();
  }
  if (t < nbkt) bb[t] = sb[t] - v;  // exclusive
  if (t == 0) bb[nbkt] = sb[nbkt - 1];
}

// ---------------------------------------------------------------------------
// One block per bucket: exact CSR sort within the bucket + emit off[] row
// ends from a 256-entry LDS histogram/scan. Scatter writes land inside the
// bucket's own 64KB output window (L2-resident), so HBM write amp is small.
__global__ __launch_bounds__(512) void bucket_sort_kernel(
    const uint2* __restrict__ PB, const int* __restrict__ bcnt,
    const int* __restrict__ bbase, uint2* __restrict__ dst,
    int* __restrict__ off, int E, int N, int nbkt, int cap) {
  PB    += (size_t)blockIdx.y * nbkt * cap;
  bcnt  += blockIdx.y * nbkt;
  bbase += blockIdx.y * (nbkt + 1);
  dst   += (size_t)blockIdx.y * E;
  off   += (size_t)blockIdx.y * N;
  int b = blockIdx.x;
  const uint2* src = PB + (size_t)b * cap;
  int cnt = min(bcnt[b], cap);
  int s = bbase[b];
  int rowbase = b << 8;
  int nrows = min(RPB, N - rowbase);

  __shared__ int rcnt[RPB];
  __shared__ int rend[RPB];   // inclusive scan
  __shared__ int lcur[RPB];
  if (threadIdx.x < RPB) rcnt[threadIdx.x] = 0;
  __syncthreads();
  for (int i = threadIdx.x; i < cnt; i += 512)
    atomicAdd(&rcnt[src[i].x >> 17], 1);
  __syncthreads();
  if (threadIdx.x < RPB) rend[threadIdx.x] = rcnt[threadIdx.x];
  __syncthreads();
  for (int st = 1; st < RPB; st <<= 1) {
    int u = 0;
    if (threadIdx.x < RPB && threadIdx.x >= st) u = rend[threadIdx.x - st];
    __syncthreads();
    if (threadIdx.x < RPB) rend[threadIdx.x] += u;
    __syncthreads();
  }
  if (threadIdx.x < nrows) off[rowbase + threadIdx.x] = s + rend[threadIdx.x];
  if (threadIdx.x < RPB)
    lcur[threadIdx.x] = s + rend[threadIdx.x] - rcnt[threadIdx.x];
  __syncthreads();
  for (int i = threadIdx.x; i < cnt; i += 512) {
    uint2 rec = src[i];
    int pos = atomicAdd(&lcur[rec.x >> 17], 1);
    dst[pos] = make_uint2(rec.x & 0x1FFFFu, rec.y);
  }
}

// ---------------------------------------------------------------------------
// Gather SpMM: wave per row, lane = feature. Edge records fetched COALESCED
// (lane l loads record s+l) and broadcast via shfl; 8 gathers in flight per
// group. nt loads/stores keep streaming records/outputs from evicting xin
// rows out of L2. remap=1: op0 -> chan0 (hA), op1..3 -> chan3..5 (hs1..3).
__global__ __launch_bounds__(256) void spmm_gather(const uint2* __restrict__ S,
    const int* __restrict__ offEnd, const float* __restrict__ xin,
    float* __restrict__ out, int N, int Estride, int remap) {
  int op = blockIdx.y;
  S      += (size_t)op * Estride;
  offEnd += (size_t)op * N;
  int ch = remap ? ((op == 0) ? 0 : (op + 2)) : op;
  out    += (size_t)ch * (size_t)N * OUT_F;
  int lane = threadIdx.x & 63;
  int r = (blockIdx.x * 256 + threadIdx.x) >> 6;
  if (r >= N) return;
  r = __builtin_amdgcn_readfirstlane(r);
  int s = (r == 0) ? 0 : offEnd[r - 1];
  int e = offEnd[r];
  float acc = 0.f;
  for (int base = s; base < e; base += 64) {
    int m = e - base;
    if (m > 64) m = 64;
    uint2v rec = (uint2v)0u;
    if (lane < m)
      rec = __builtin_nontemporal_load((const uint2v*)S + (base + lane));
    int k = 0;
    for (; k + 8 <= m; k += 8) {
#pragma unroll
      for (int u = 0; u < 8; ++u) {
        int c = __shfl((int)rec.x, k + u);
        float w = __uint_as_float((unsigned)__shfl((int)rec.y, k + u));
        acc = fmaf(w, xin[(size_t)(unsigned)c * OUT_F + lane], acc);
      }
    }
    for (; k < m; ++k) {
      int c = __shfl((int)rec.x, k);
      float w = __uint_as_float((unsigned)__shfl((int)rec.y, k));
      acc = fmaf(w, xin[(size_t)(unsigned)c * OUT_F + lane], acc);
    }
  }
  __builtin_nontemporal_store(acc, &out[(size_t)r * OUT_F + lane]);
}

// ---------------------------------------------------------------------------
// Fused epilogue. (proven kernel, unchanged)
__global__ __launch_bounds__(256) void fuse_kernel(const float* __restrict__ s0,
    const float* __restrict__ chan, const float* __restrict__ a,
    float* __restrict__ out_h, float* __restrict__ out_att, int N) {
  int lane = threadIdx.x & 63;
  int i = (blockIdx.x * blockDim.x + threadIdx.x) >> 6;
  if (i >= N) return;
  size_t NF = (size_t)N * OUT_F;
  float e[6];
  int half = N >> 1;
  if (i < half) {
    float lo = s0[(size_t)(2 * i) * OUT_F + lane];
    float hi = s0[(size_t)(2 * i + 1) * OUT_F + lane];
#pragma unroll
    for (int ch = 0; ch < 6; ++ch) {
      float p = fmaf(lo, a[ch * 128 + lane], hi * a[ch * 128 + 64 + lane]);
#pragma unroll
      for (int off = 32; off; off >>= 1) p += __shfl_xor(p, off);
      e[ch] = p;
    }
  } else {
    int r = 2 * i - N;
#pragma unroll
    for (int ch = 0; ch < 6; ++ch) {
      float lo = chan[(size_t)ch * NF + (size_t)r * OUT_F + lane];
      float hi = chan[(size_t)ch * NF + (size_t)(r + 1) * OUT_F + lane];
      if (ch >= 3) { lo = fabsf(lo); hi = fabsf(hi); }
      float p = fmaf(lo, a[ch * 128 + lane], hi * a[ch * 128 + 64 + lane]);
#pragma unroll
      for (int off = 32; off; off >>= 1) p += __shfl_xor(p, off);
      e[ch] = p;
    }
  }
  float m = e[0];
#pragma unroll
  for (int ch = 1; ch < 6; ++ch) m = fmaxf(m, e[ch]);
  float s = 0.f;
#pragma unroll
  for (int ch = 0; ch < 6; ++ch) { e[ch] = expf(e[ch] - m); s += e[ch]; }
  float inv = 1.f / s;
#pragma unroll
  for (int ch = 0; ch < 6; ++ch) e[ch] *= inv;

  if (lane < 6) {
    float v = e[0];
    if (lane == 1) v = e[1];
    if (lane == 2) v = e[2];
    if (lane == 3) v = e[3];
    if (lane == 4) v = e[4];
    if (lane == 5) v = e[5];
    out_att[(size_t)i * 6 + lane] = v;
  }

  float hp = 0.f;
#pragma unroll
  for (int p = 0; p < 6; ++p) {
    int idx = p * 64 + lane;
    int c = idx % 6;
    int j = idx / 6;
    float v = chan[(size_t)c * NF + (size_t)i * OUT_F + j];
    v = (c >= 3) ? fabsf(v) : v;
    hp = fmaf(e[p], v, hp);
  }
  out_h[(size_t)i * OUT_F + lane] = hp * (1.f / 6.f);
}

// ---------------------------------------------------------------------------
extern "C" void kernel_launch(void* const* d_in, const int* in_sizes, int n_in,
                              void* d_out, int out_size, void* d_ws, size_t ws_size,
                              hipStream_t stream) {
  const float* x      = (const float*)d_in[0];
  const float* W      = (const float*)d_in[1];
  const float* a      = (const float*)d_in[2];
  const int*   A_idx  = (const int*)d_in[3];
  const float* A_val  = (const float*)d_in[4];
  const int*   P1_idx = (const int*)d_in[5];
  const float* P1_val = (const float*)d_in[6];
  const int*   P2_idx = (const int*)d_in[7];
  const float* P2_val = (const float*)d_in[8];
  const int*   P3_idx = (const int*)d_in[9];
  const float* P3_val = (const float*)d_in[10];

  int N = in_sizes[0] / IN_F;      // 100000
  int E = in_sizes[4];             // 3200000
  int nbkt = (N + RPB - 1) / RPB;  // 391 (<= NBKT_MAX)

  size_t NF = (size_t)N * OUT_F;
  float* s0   = (float*)d_ws;
  float* chan = s0 + NF;               // 6 contiguous [N,64] channel buffers
  float* hA   = chan + 0 * NF;
  float* hA2  = chan + 1 * NF;
  float* hA3  = chan + 2 * NF;
  float* hs1  = chan + 3 * NF;

  float* out_h   = (float*)d_out;
  float* out_att = out_h + NF;

  int fblocks = (N * 64 + 255) / 256;
  int gblocks = (N * 64 + 255) / 256;
  int binblocks = (E + BIN_C - 1) / BIN_C;

  // Padded-bucket capacity: mean + 25% + 256 (>25 sigma for uniform rows).
  int cap = E / nbkt + E / (4 * nbkt) + 256;
  // PB aliases chan; make sure 4 padded ops fit inside chan's 6NF floats.
  size_t pbcap_max = (6 * NF * 4) / ((size_t)4 * nbkt * 8);
  if ((size_t)cap > pbcap_max) cap = (int)pbcap_max;

  gemm_kernel<<<512, 256, 0, stream>>>(x, W, s0, N);

  // Primary layout: PB aliases chan (4*391*10486*8B = 131MB <= 153.6MB);
  // PB is dead before the first spmm_gather writes chan.
  uint2* PB   = (uint2*)chan;
  uint2* S    = (uint2*)(chan + 6 * NF);  // sorted CSR records, 4E
  int* off    = (int*)(S + (size_t)4 * E);
  int* bcur   = off + 4 * N;
  int* bbase  = bcur + 4 * nbkt;
  size_t need = (size_t)((char*)(bbase + 4 * (nbkt + 1)) - (char*)d_ws);

  if (ws_size >= need) {
    // ---- all 4 operators through one batched padded-bin pipeline ----
    zero_i_kernel<<<4, 256, 0, stream>>>(bcur, 4 * nbkt);
    bin_kernel<<<dim3(binblocks, 4), BIN_T, 0, stream>>>(A_idx, P1_idx, P2_idx,
        P3_idx, A_val, P1_val, P2_val, P3_val, bcur, PB, E, nbkt, cap, 0);
    bscan_kernel<<<4, 512, 0, stream>>>(bcur, bbase, nbkt);
    bucket_sort_kernel<<<dim3(nbkt, 4), 512, 0, stream>>>(PB, bcur, bbase, S,
        off, E, N, nbkt, cap);
    // First-level SpMMs (A,P1,P2,P3 all read s0) in one batch, then A chain.
    spmm_gather<<<dim3(gblocks, 4), 256, 0, stream>>>(S, off, s0, chan, N, E, 1);
    spmm_gather<<<dim3(gblocks, 1), 256, 0, stream>>>(S, off, hA,  hA2, N, 0, 0);
    spmm_gather<<<dim3(gblocks, 1), 256, 0, stream>>>(S, off, hA2, hA3, N, 0, 0);
  } else {
    // ---- sequential fallback: disjoint S1/PB1 regions, one op at a time ----
    uint2* S1    = (uint2*)(chan + 6 * NF);        // E sorted records
    uint2* PB1   = S1 + E;                         // nbkt*cap padded records
    int* off1    = (int*)(PB1 + (size_t)nbkt * cap);  // 4N (per-op slices)
    int* bcur1   = off1 + 4 * N;
    int* bbase1  = bcur1 + nbkt;
    for (int o = 0; o < 4; ++o) {
      zero_i_kernel<<<1, 256, 0, stream>>>(bcur1, nbkt);
      bin_kernel<<<dim3(binblocks, 1), BIN_T, 0, stream>>>(A_idx, P1_idx, P2_idx,
          P3_idx, A_val, P1_val, P2_val, P3_val, bcur1, PB1, E, nbkt, cap, o);
      bscan_kernel<<<1, 512, 0, stream>>>(bcur1, bbase1, nbkt);
      bucket_sort_kernel<<<dim3(nbkt, 1), 512, 0, stream>>>(PB1, bcur1, bbase1,
          S1, off1 + o * N, E, N, nbkt, cap);
      if (o == 0) {
        spmm_gather<<<dim3(gblocks, 1), 256, 0, stream>>>(S1, off1, s0,  hA,  N, 0, 0);
        spmm_gather<<<dim3(gblocks, 1), 256, 0, stream>>>(S1, off1, hA,  hA2, N, 0, 0);
        spmm_gather<<<dim3(gblocks, 1), 256, 0, stream>>>(S1, off1, hA2, hA3, N, 0, 0);
      } else {
        spmm_gather<<<dim3(gblocks, 1), 256, 0, stream>>>(S1, off1 + o * N, s0,
            hs1 + (size_t)(o - 1) * NF, N, 0, 0);
      }
    }
  }

  fuse_kernel<<<fblocks, 256, 0, stream>>>(s0, chan, a, out_h, out_att, N);
}